// Round 2
// 284.916 us; speedup vs baseline: 1.0806x; 1.0806x over previous
//
#include <hip/hip_runtime.h>

// B=2, S=2048, D=1024, H=16, DK=64.  I/O fp32; internal MFMA pipeline bf16.
typedef __bf16 bf16x8 __attribute__((ext_vector_type(8)));
typedef float  f32x4  __attribute__((ext_vector_type(4)));

#define AS1 __attribute__((address_space(1)))
#define AS3 __attribute__((address_space(3)))

__device__ __forceinline__ void g2l16(const void* g, void* l) {
  __builtin_amdgcn_global_load_lds((AS1 void*)g, (AS3 void*)l, 16, 0, 0);
}
#define MFMA16(a, b, c) __builtin_amdgcn_mfma_f32_16x16x32_bf16(a, b, c, 0, 0, 0)

__device__ __forceinline__ unsigned pack_bf16(float a, float b) {
  union { __bf16 h[2]; unsigned u; } p;
  p.h[0] = (__bf16)a; p.h[1] = (__bf16)b;
  return p.u;
}

// ---------------- fused prep: cvt x3 | mask -> KEEP bitmask | transpose_w4 ----------------
__global__ __launch_bounds__(256) void prep(const float* __restrict__ inQ,
    const float* __restrict__ inK, const float* __restrict__ inV,
    const int* __restrict__ mask,
    const float* __restrict__ W0, const float* __restrict__ W1,
    const float* __restrict__ W2, const float* __restrict__ W3,
    __bf16* __restrict__ Xq, __bf16* __restrict__ Xk, __bf16* __restrict__ Xv,
    unsigned long long* __restrict__ bits, __bf16* __restrict__ Wt) {
  __shared__ __bf16 tile[64][65];
  const int blk = blockIdx.x;
  if (blk < 6144) {
    const int z = blk >> 11, bx = blk & 2047;
    const float* src = z == 0 ? inQ : (z == 1 ? inK : inV);
    __bf16* dst = z == 0 ? Xq : (z == 1 ? Xk : Xv);
    size_t base = ((size_t)bx * 256 + threadIdx.x) * 8;
    float4 f0 = *(const float4*)(src + base);
    float4 f1 = *(const float4*)(src + base + 4);
    bf16x8 o;
    o[0] = (__bf16)f0.x; o[1] = (__bf16)f0.y; o[2] = (__bf16)f0.z; o[3] = (__bf16)f0.w;
    o[4] = (__bf16)f1.x; o[5] = (__bf16)f1.y; o[6] = (__bf16)f1.z; o[7] = (__bf16)f1.w;
    *(bf16x8*)(dst + base) = o;
  } else if (blk < 10240) {
    const int lane = threadIdx.x & 63, w = threadIdx.x >> 6;
    const int base = (blk - 6144) * 2048 + w * 512;
#pragma unroll
    for (int it = 0; it < 8; ++it) {
      int i = base + it * 64 + lane;
      // KEEP bit (mask==0): attn zeroes p via sign-extended AND, 1 op cheaper than cndmask
      unsigned long long bb = __ballot(mask[i] == 0);
      if (lane == 0) bits[i >> 6] = bb;
    }
  } else {
    const int idx = blk - 10240;
    const int z = idx >> 8, rem = idx & 255, bx = rem & 15, by = rem >> 4;
    const float* srcs[4] = {W0, W1, W2, W3};
    const float* src = srcs[z];
    __bf16* dst = Wt + (size_t)z * 1024 * 1024;
    int cb = bx * 64, rb = by * 64;
    for (int i = threadIdx.x; i < 4096; i += 256) {
      int r = i >> 6, c = i & 63;
      tile[r][c] = (__bf16)src[(size_t)(rb + r) * 1024 + cb + c];
    }
    __syncthreads();
    for (int i = threadIdx.x; i < 4096; i += 256) {
      int c = i >> 6, r = i & 63;
      dst[(size_t)(cb + c) * 1024 + rb + r] = tile[r][c];
    }
  }
}

// ---------------- QKV projection GEMM, 128x128 tile, BK=32 ----------------
// z=0: Q scaled by log2e/8.  z=1: K.  z=2: V -> V^T [BH][DK][S] via LDS restage,
// with per-32-chunk t-permutation slot(t)=8*((t>>2)&3)+4*((t>>4)&1)+(t&3) so that
// attn's exp2 outputs feed the PV A-fragment directly from registers (no P LDS).
__global__ __launch_bounds__(256) void qkv_gemm(const __bf16* __restrict__ Xq,
    const __bf16* __restrict__ Xk, const __bf16* __restrict__ Xv,
    const __bf16* __restrict__ Wt, __bf16* __restrict__ Qb,
    __bf16* __restrict__ Kb, __bf16* __restrict__ Vtb) {
  __shared__ __align__(16) __bf16 sh[8192];   // As | Bs; reused as 64x128 transpose buf
  __bf16* As = sh;
  __bf16* Bs = sh + 4096;
  const int z = blockIdx.z;
  const __bf16* X = z == 0 ? Xq : (z == 1 ? Xk : Xv);
  const __bf16* W = Wt + (size_t)z * 1048576;
  const float scale = z == 0 ? 0.125f * 1.44269504088896f : 1.f;
  const int t = threadIdx.x;
  const int lane = t & 63, w = t >> 6;
  const int lane15 = lane & 15, quad = lane >> 4;
  const int wm = (w >> 1) * 64, wn = (w & 1) * 64;
  const int mBase = blockIdx.y * 128, nBase = blockIdx.x * 128;
  const int c1 = t, c2 = t + 256;
  f32x4 acc[4][4] = {};
  for (int kt = 0; kt < 1024; kt += 32) {
    __syncthreads();
    g2l16(X + (size_t)(mBase + (c1 >> 2)) * 1024 + kt + (c1 & 3) * 8, As + c1 * 8);
    g2l16(X + (size_t)(mBase + (c2 >> 2)) * 1024 + kt + (c2 & 3) * 8, As + c2 * 8);
    g2l16(W + (size_t)(nBase + (c1 >> 2)) * 1024 + kt + (c1 & 3) * 8, Bs + c1 * 8);
    g2l16(W + (size_t)(nBase + (c2 >> 2)) * 1024 + kt + (c2 & 3) * 8, Bs + c2 * 8);
    __builtin_amdgcn_s_waitcnt(0);
    __syncthreads();
    bf16x8 a[4], b[4];
#pragma unroll
    for (int i = 0; i < 4; i++) a[i] = *(const bf16x8*)&As[(wm + i * 16 + lane15) * 32 + quad * 8];
#pragma unroll
    for (int j = 0; j < 4; j++) b[j] = *(const bf16x8*)&Bs[(wn + j * 16 + lane15) * 32 + quad * 8];
#pragma unroll
    for (int i = 0; i < 4; i++)
#pragma unroll
      for (int j = 0; j < 4; j++)
        acc[i][j] = MFMA16(a[i], b[j], acc[i][j]);
  }
  if (z != 2) {
    __bf16* Y = z == 0 ? Qb : Kb;
#pragma unroll
    for (int i = 0; i < 4; i++)
#pragma unroll
      for (int j = 0; j < 4; j++)
#pragma unroll
        for (int r = 0; r < 4; r++) {
          int mg = mBase + wm + i * 16 + quad * 4 + r;
          int ng = nBase + wn + j * 16 + lane15;
          int b_ = mg >> 11, s_ = mg & 2047, h_ = ng >> 6, d_ = ng & 63;
          Y[(((size_t)(b_ * 16 + h_)) * 2048 + s_) * 64 + d_] = (__bf16)(acc[i][j][r] * scale);
        }
  } else {
    const int s0 = mBase & 2047;
    const int bhBase = (mBase >> 11) * 16 + (nBase >> 6);
#pragma unroll
    for (int half = 0; half < 2; ++half) {
      __syncthreads();
      if ((w & 1) == half) {
#pragma unroll
        for (int i = 0; i < 4; i++)
#pragma unroll
          for (int j = 0; j < 4; j++)
#pragma unroll
            for (int r = 0; r < 4; r++) {
              int nl = j * 16 + lane15;
              int ml = wm + i * 16 + quad * 4 + r;
              // within-32 t-permutation to match attn's in-register P fragment
              int l5 = ml & 31;
              int mlp = (ml & 96) | ((((l5 >> 2) & 3) * 8) + (l5 & 3) + (((l5 >> 4) & 1) * 4));
              sh[nl * 128 + (mlp ^ ((nl & 7) * 16))] = (__bf16)acc[i][j][r];
            }
      }
      __syncthreads();
      const int row = t >> 2, c0 = (t & 3) * 32;
      const int xr = (row & 7) * 16;
      const int b0 = row * 128 + (c0 ^ xr);
      const int b1 = row * 128 + ((c0 + 16) ^ xr);
      bf16x8 a0 = *(const bf16x8*)&sh[b0];
      bf16x8 a1 = *(const bf16x8*)&sh[b0 + 8];
      bf16x8 a2 = *(const bf16x8*)&sh[b1];
      bf16x8 a3 = *(const bf16x8*)&sh[b1 + 8];
      __bf16* dst = Vtb + (size_t)(bhBase + half) * 131072 + (size_t)row * 2048 + s0 + c0;
      *(bf16x8*)(dst)      = a0;
      *(bf16x8*)(dst + 8)  = a1;
      *(bf16x8*)(dst + 16) = a2;
      *(bf16x8*)(dst + 24) = a3;
    }
  }
}

// ---------------- output projection + fp32 residual, 64x128 tile ----------------
__global__ __launch_bounds__(256) void gemm_wo(const __bf16* __restrict__ X,
    const __bf16* __restrict__ Wt, const float* __restrict__ resid,
    float* __restrict__ Yf) {
  __shared__ __align__(16) __bf16 As[64 * 32];
  __shared__ __align__(16) __bf16 Bs[128 * 32];
  const int t = threadIdx.x;
  const int lane = t & 63, w = t >> 6;
  const int lane15 = lane & 15, quad = lane >> 4;
  const int wm = (w >> 1) * 32, wn = (w & 1) * 64;
  const int mBase = blockIdx.y * 64, nBase = blockIdx.x * 128;
  f32x4 acc[2][4] = {};
  for (int kt = 0; kt < 1024; kt += 32) {
    __syncthreads();
    g2l16(X  + (size_t)(mBase + (t >> 2)) * 1024 + kt + (t & 3) * 8, As + t * 8);
    g2l16(Wt + (size_t)(nBase + (t >> 2)) * 1024 + kt + (t & 3) * 8, Bs + t * 8);
    g2l16(Wt + (size_t)(nBase + ((t + 256) >> 2)) * 1024 + kt + (t & 3) * 8, Bs + (t + 256) * 8);
    __builtin_amdgcn_s_waitcnt(0);
    __syncthreads();
    bf16x8 a[2], b[4];
#pragma unroll
    for (int i = 0; i < 2; i++) a[i] = *(const bf16x8*)&As[(wm + i * 16 + lane15) * 32 + quad * 8];
#pragma unroll
    for (int j = 0; j < 4; j++) b[j] = *(const bf16x8*)&Bs[(wn + j * 16 + lane15) * 32 + quad * 8];
#pragma unroll
    for (int i = 0; i < 2; i++)
#pragma unroll
      for (int j = 0; j < 4; j++)
        acc[i][j] = MFMA16(a[i], b[j], acc[i][j]);
  }
#pragma unroll
  for (int i = 0; i < 2; i++)
#pragma unroll
    for (int j = 0; j < 4; j++)
#pragma unroll
      for (int r = 0; r < 4; r++) {
        int mg = mBase + wm + i * 16 + quad * 4 + r;
        int ng = nBase + wn + j * 16 + lane15;
        size_t idx = (size_t)mg * 1024 + ng;
        Yf[idx] = acc[i][j][r] + resid[idx];
      }
}

// ---------------- flash attention: 16x16, t-tile 32, P kept fully in registers ----------------
// Per iter kt: QK(kt) -> PV(kt-1) (independent MFMAs fill the MFMA->exp2 gap) ->
// exp2+mask+pack(kt) straight into the PV A-fragment (consumed next iter).
// A slot (quad,idx) holds t = 16*(idx>>2) + 4*quad + (idx&3); Vtb carries the matching
// within-32 t-permutation, so NO LDS round-trip / lgkmcnt drain / bank conflicts for P.
// Vs 4-deep (stage kt+1 while reading kt-1). LDS 32KB.
// Swizzles: 64-col rows: chunk^(row&7); 32-col rows: chunk^((row>>1)&3).
__global__ __launch_bounds__(256) void attn_kernel(const __bf16* __restrict__ Q,
    const __bf16* __restrict__ Kp, const __bf16* __restrict__ Vt,
    const unsigned* __restrict__ mbits, __bf16* __restrict__ ctx) {
  __shared__ __align__(16) __bf16 Qs[64 * 64];        // 8KB [q][dk]
  __shared__ __align__(16) __bf16 Ks[2][32 * 64];     // 8KB [t][dk]
  __shared__ __align__(16) __bf16 Vs[4][64 * 32];     // 16KB [d][t-permuted]
  const int t = threadIdx.x, lane = t & 63, w = t >> 6;
  const int l15 = lane & 15, quad = lane >> 4;
  const int bh = blockIdx.y, b = bh >> 4, h = bh & 15;
  const int qBase = blockIdx.x * 64;
  const size_t qko = (size_t)bh * 2048 * 64;
  const size_t vko = (size_t)bh * 64 * 2048;
  const int srow8 = lane >> 3, sch8 = (lane & 7) ^ srow8;
  const int srow16 = lane >> 2, sch4 = (lane & 3) ^ ((lane >> 3) & 3);
  g2l16(Q + qko + (size_t)(qBase + w * 8 + srow8) * 64 + sch8 * 8,       Qs + w * 512 + lane * 8);
  g2l16(Q + qko + (size_t)(qBase + (w + 4) * 8 + srow8) * 64 + sch8 * 8, Qs + (w + 4) * 512 + lane * 8);
  g2l16(Kp + qko + (size_t)(w * 8 + srow8) * 64 + sch8 * 8,     &Ks[0][0] + w * 512 + lane * 8);
  g2l16(Vt + vko + (size_t)(w * 16 + srow16) * 2048 + sch4 * 8, &Vs[0][0] + w * 512 + lane * 8);
  const size_t mIdx = ((size_t)b * 2048 + qBase + w * 16 + l15) * 64;
  unsigned m32 = mbits[mIdx];
  __builtin_amdgcn_s_waitcnt(0);
  __syncthreads();
  bf16x8 qb0, qb1;
  {
    const int r = w * 16 + l15, s = r & 7;
    qb0 = *(const bf16x8*)&Qs[r * 64 + ((quad ^ s) * 8)];
    qb1 = *(const bf16x8*)&Qs[r * 64 + (((4 + quad) ^ s) * 8)];
  }
  bf16x8 ones;
#pragma unroll
  for (int i = 0; i < 8; i++) ones[i] = (__bf16)1.0f;
  f32x4 o[4] = {};
  f32x4 ol = {};
  bf16x8 pa_prev;
#pragma unroll 4
  for (int kt = 0; kt < 64; ++kt) {
    __syncthreads();   // implicit vmcnt(0)+lgkm(0): staging of tile kt complete
    unsigned mnext = 0;
    if (kt < 63) {
      const int tB = (kt + 1) * 32;
      g2l16(Kp + qko + (size_t)(tB + w * 8 + srow8) * 64 + sch8 * 8,     &Ks[(kt + 1) & 1][0] + w * 512 + lane * 8);
      g2l16(Vt + vko + (size_t)(w * 16 + srow16) * 2048 + tB + sch4 * 8, &Vs[(kt + 1) & 3][0] + w * 512 + lane * 8);
      mnext = mbits[mIdx + kt + 1];
    }
    // S^T(kt) = K·Q^T : lane holds q=l15, t = j*16 + quad*4 + r
    f32x4 st[2];
#pragma unroll
    for (int j = 0; j < 2; j++) {
      const int tr = j * 16 + l15, s = tr & 7;
      bf16x8 ka0 = *(const bf16x8*)&Ks[kt & 1][tr * 64 + ((quad ^ s) * 8)];
      bf16x8 ka1 = *(const bf16x8*)&Ks[kt & 1][tr * 64 + (((4 + quad) ^ s) * 8)];
      f32x4 zz = {0.f, 0.f, 0.f, 0.f};
      zz = MFMA16(ka0, qb0, zz);
      st[j] = MFMA16(ka1, qb1, zz);
    }
    // PV(kt-1): independent of st -> fills the MFMA->exp2 latency gap
    if (kt > 0) {
      const __bf16* Vb = &Vs[(kt - 1) & 3][0];
      ol = MFMA16(pa_prev, ones, ol);
#pragma unroll
      for (int j = 0; j < 4; j++) {
        const int dr = j * 16 + l15;
        bf16x8 vb = *(const bf16x8*)&Vb[dr * 32 + ((quad ^ ((dr >> 1) & 3)) * 8)];
        o[j] = MFMA16(pa_prev, vb, o[j]);
      }
    }
    // p = exp2(s) & keepbit, packed directly into the PV A-fragment (registers only)
    {
      const unsigned msh = m32 >> (quad * 4);   // bit (j*16+r) of msh == keep bit for t
      union { unsigned u[4]; bf16x8 v; } pk;
#pragma unroll
      for (int j = 0; j < 2; j++) {
        float e[4];
#pragma unroll
        for (int r = 0; r < 4; r++) {
          int sel = ((int)(msh << (31 - (j * 16 + r)))) >> 31;   // keep ? -1 : 0
          float ev = __builtin_exp2f(st[j][r]);
          e[r] = __uint_as_float(__float_as_uint(ev) & (unsigned)sel);
        }
        pk.u[2 * j]     = pack_bf16(e[0], e[1]);
        pk.u[2 * j + 1] = pack_bf16(e[2], e[3]);
      }
      pa_prev = pk.v;
    }
    m32 = mnext;
  }
  // drain: PV(63)
  {
    const __bf16* Vb = &Vs[63 & 3][0];
    ol = MFMA16(pa_prev, ones, ol);
#pragma unroll
    for (int j = 0; j < 4; j++) {
      const int dr = j * 16 + l15;
      bf16x8 vb = *(const bf16x8*)&Vb[dr * 32 + ((quad ^ ((dr >> 1) & 3)) * 8)];
      o[j] = MFMA16(pa_prev, vb, o[j]);
    }
  }
#pragma unroll
  for (int r = 0; r < 4; r++) {
    float inv = 1.f / ol[r];
    int qg = qBase + w * 16 + quad * 4 + r;
    size_t base = ((size_t)b * 2048 + qg) * 1024 + h * 64;
#pragma unroll
    for (int j = 0; j < 4; j++)
      ctx[base + j * 16 + l15] = (__bf16)(o[j][r] * inv);
  }
}

// ---------------- LayerNorm over D=1024 per row (fp32) ----------------
__global__ __launch_bounds__(256) void ln_kernel(const float* __restrict__ X,
    const float* __restrict__ gamma, const float* __restrict__ beta,
    float* __restrict__ out) {
  __shared__ float red[8];
  const int t = threadIdx.x;
  const size_t row = blockIdx.x;
  const float* xr = X + row * 1024;
  float4 x = *(const float4*)(xr + t * 4);
  float s = x.x + x.y + x.z + x.w;
  float s2 = x.x * x.x + x.y * x.y + x.z * x.z + x.w * x.w;
#pragma unroll
  for (int off = 1; off < 64; off <<= 1) { s += __shfl_xor(s, off); s2 += __shfl_xor(s2, off); }
  if ((t & 63) == 0) { red[t >> 6] = s; red[4 + (t >> 6)] = s2; }
  __syncthreads();
  float S1 = red[0] + red[1] + red[2] + red[3];
  float S2 = red[4] + red[5] + red[6] + red[7];
  float mu = S1 * (1.f / 1024.f);
  float var = S2 * (1.f / 1024.f) - mu * mu;
  float rs = rsqrtf(var + 1e-5f);
  float4 g = *(const float4*)(gamma + t * 4);
  float4 bb = *(const float4*)(beta + t * 4);
  float4 y;
  y.x = (x.x - mu) * rs * g.x + bb.x;
  y.y = (x.y - mu) * rs * g.y + bb.y;
  y.z = (x.z - mu) * rs * g.z + bb.z;
  y.w = (x.w - mu) * rs * g.w + bb.w;
  *(float4*)(out + row * 1024 + t * 4) = y;
}

extern "C" void kernel_launch(void* const* d_in, const int* in_sizes, int n_in,
                              void* d_out, int out_size, void* d_ws, size_t ws_size,
                              hipStream_t stream) {
  const float* inQ  = (const float*)d_in[0];
  const float* inK  = (const float*)d_in[1];
  const float* inV  = (const float*)d_in[2];
  const int*   mask = (const int*)d_in[3];
  const float* WQ   = (const float*)d_in[4];
  const float* WK   = (const float*)d_in[5];
  const float* WV   = (const float*)d_in[6];
  const float* WO   = (const float*)d_in[7];
  const float* gamma = (const float*)d_in[8];
  const float* beta  = (const float*)d_in[9];

  const size_t MB = 1024 * 1024;
  char* ws = (char*)d_ws;
  __bf16* Xq  = (__bf16*)(ws);                    // 8 MB each
  __bf16* Xk  = (__bf16*)(ws + 8 * MB);
  __bf16* Xv  = (__bf16*)(ws + 16 * MB);
  __bf16* Qb  = (__bf16*)(ws + 24 * MB);          // [BH][S][DK]
  __bf16* Kb  = (__bf16*)(ws + 32 * MB);
  __bf16* Vtb = (__bf16*)(ws + 48 * MB);          // [BH][DK][S] (t-permuted per 32)
  __bf16* Wt  = (__bf16*)(ws + 56 * MB);          // 4x 2MB bf16^T weights
  unsigned long long* mbits = (unsigned long long*)(ws + 64 * MB);  // 1 MB (KEEP bits)
  __bf16* ctx  = Xq;                              // reuse
  float*  outp = (float*)(ws + 8 * MB);           // reuse Xk+Xv

  prep<<<dim3(11264), 256, 0, stream>>>(inQ, inK, inV, mask, WQ, WK, WV, WO,
                                        Xq, Xk, Xv, mbits, Wt);
  qkv_gemm<<<dim3(8, 32, 3), 256, 0, stream>>>(Xq, Xk, Xv, Wt, Qb, Kb, Vtb);
  attn_kernel<<<dim3(32, 32), 256, 0, stream>>>(Qb, Kb, Vtb, (const unsigned*)mbits, ctx);
  gemm_wo<<<dim3(8, 64), 256, 0, stream>>>(ctx, Wt + 3 * 1048576, inQ, outp);
  ln_kernel<<<dim3(4096), 256, 0, stream>>>(outp, gamma, beta, (float*)d_out);
}